// Round 1
// baseline (209.472 us; speedup 1.0000x reference)
//
#include <hip/hip_runtime.h>

// GraphAttention fused forward for MI355X (gfx950).
// v2: single fused attn kernel — wave = j-quarter x all-4-heads (kills the 4x
// LDS re-read of adj/msk), global_load_lds double-buffered staging with
// XOR-swizzled source (conflict-free ds_read_b128), epilogue (softmax /l,
// bias, BN, ReLU, transpose, out) fused in; part/lpart/final_kernel removed.
// B=4, N=2048, F=64, FP=32, H=4.  Output: [B,N,H*FP] f32 ++ uloss ++ eloss.

#define B_ 4
#define N_ 2048
#define F_ 64
#define FP_ 32
#define H_ 4
#define C_ 128
#define IT_ 32                 // i-rows per block (2 per lane)
#define ITILES_ (N_ / IT_)     // 64
#define JST_ 128               // j per LDS stage
#define NST_ (N_ / JST_)       // 16 stages

typedef __attribute__((ext_vector_type(8))) short short8v;   // 8 bf16 = 4 VGPRs
typedef __attribute__((ext_vector_type(4))) float f32x4;     // MFMA C/D
typedef __attribute__((ext_vector_type(4))) int   int4v;

union PkU { int4v i; short8v s; };

__device__ __forceinline__ unsigned short f2bf(float f) {    // RNE fp32->bf16
    unsigned u = __float_as_uint(f);
    u += 0x7fffu + ((u >> 16) & 1u);
    return (unsigned short)(u >> 16);
}

// 8 elementwise attn values -> l,A accumulate + packed bf16 A-frag dword x4.
__device__ __forceinline__ void attn_qstep(
    float si, const float* av, const float* mv, const float* tv,
    float& l, float& A, int4v& apk)
{
#pragma unroll
    for (int qq = 0; qq < 4; ++qq) {
        float d0 = si + tv[2 * qq];
        d0 = fmaxf(d0, 0.2f * d0) + mv[2 * qq];       // LeakyReLU(0.2) + mask
        float e0 = __expf(d0);                        // bounded: no max-subtract
        float p0 = e0 * av[2 * qq];
        float d1 = si + tv[2 * qq + 1];
        d1 = fmaxf(d1, 0.2f * d1) + mv[2 * qq + 1];
        float e1 = __expf(d1);
        float p1 = e1 * av[2 * qq + 1];
        l += e0 + e1;
        A += p0 + p1;
        unsigned u0 = __float_as_uint(p0) + 0x8000u;  // round-half-up, p>=0
        unsigned u1 = __float_as_uint(p1) + 0x8000u;
        apk[qq] = (int)__builtin_amdgcn_perm(u1, u0, 0x07060302u); // [p1.hi|p0.hi]
    }
}

// async global->LDS, 16 B per lane; LDS dest wave-uniform base + lane*16.
__device__ __forceinline__ void gl_lds16(const float* g, float* l) {
    __builtin_amdgcn_global_load_lds(
        (const __attribute__((address_space(1))) unsigned*)g,
        (__attribute__((address_space(3))) unsigned*)l, 16, 0, 0);
}

// ---------------------------------------------------------------- kernel 1
// feats = x@W per head via MFMA; writes featsT bf16 [b][h][d][n] + s,t fp32.
__global__ __launch_bounds__(256) void prep_kernel(
    const float* __restrict__ x, const float* __restrict__ W,
    const float* __restrict__ a_self, const float* __restrict__ a_neigh,
    unsigned short* __restrict__ featsT, float* __restrict__ sbuf,
    float* __restrict__ tbuf)
{
    int blk = blockIdx.x;              // b*32 + nt
    int b = blk >> 5, nt = blk & 31;
    int n0 = nt << 6;
    int t = threadIdx.x, h = t >> 6, lane = t & 63;
    int quad = lane >> 4, col = lane & 15;

    short8v bw[2][2];
    const float* Wh = W + (size_t)h * F_ * FP_;
#pragma unroll
    for (int kc = 0; kc < 2; ++kc)
#pragma unroll
        for (int dt = 0; dt < 2; ++dt)
#pragma unroll
            for (int e = 0; e < 8; ++e) {
                int f = kc * 32 + quad * 8 + e;
                bw[kc][dt][e] = (short)f2bf(Wh[f * FP_ + dt * 16 + col]);
            }
    float as0 = a_self[h * FP_ + col],  as1 = a_self[h * FP_ + 16 + col];
    float an0 = a_neigh[h * FP_ + col], an1 = a_neigh[h * FP_ + 16 + col];
    size_t hrow = ((size_t)b * H_ + h) * N_;
    size_t ftb  = ((size_t)b * H_ + h) * FP_;

    for (int ms = 0; ms < 4; ++ms) {
        int row = n0 + ms * 16 + col;          // A row m = lane&15
        const float* xr = x + ((size_t)b * N_ + row) * F_;
        f32x4 acc0 = {0.f, 0.f, 0.f, 0.f}, acc1 = {0.f, 0.f, 0.f, 0.f};
#pragma unroll
        for (int kc = 0; kc < 2; ++kc) {
            float4 x0 = *(const float4*)(xr + kc * 32 + quad * 8);
            float4 x1 = *(const float4*)(xr + kc * 32 + quad * 8 + 4);
            short8v av;
            av[0] = (short)f2bf(x0.x); av[1] = (short)f2bf(x0.y);
            av[2] = (short)f2bf(x0.z); av[3] = (short)f2bf(x0.w);
            av[4] = (short)f2bf(x1.x); av[5] = (short)f2bf(x1.y);
            av[6] = (short)f2bf(x1.z); av[7] = (short)f2bf(x1.w);
            acc0 = __builtin_amdgcn_mfma_f32_16x16x32_bf16(av, bw[kc][0], acc0, 0, 0, 0);
            acc1 = __builtin_amdgcn_mfma_f32_16x16x32_bf16(av, bw[kc][1], acc1, 0, 0, 0);
        }
        {   // C layout: row = quad*4+rr, col = lane&15 (verified m89/m91)
            ushort4 v0, v1;
            v0.x = f2bf(acc0[0]); v0.y = f2bf(acc0[1]);
            v0.z = f2bf(acc0[2]); v0.w = f2bf(acc0[3]);
            v1.x = f2bf(acc1[0]); v1.y = f2bf(acc1[1]);
            v1.z = f2bf(acc1[2]); v1.w = f2bf(acc1[3]);
            size_t nidx = (size_t)n0 + ms * 16 + quad * 4;
            *(ushort4*)(featsT + (ftb + col) * N_ + nidx)      = v0;
            *(ushort4*)(featsT + (ftb + 16 + col) * N_ + nidx) = v1;
        }
#pragma unroll
        for (int rr = 0; rr < 4; ++rr) {
            float sv = acc0[rr] * as0 + acc1[rr] * as1;
            float tv = acc0[rr] * an0 + acc1[rr] * an1;
#pragma unroll
            for (int off = 8; off; off >>= 1) {
                sv += __shfl_down(sv, off);
                tv += __shfl_down(tv, off);
            }
            if (col == 0) {
                int n = n0 + ms * 16 + quad * 4 + rr;
                sbuf[hrow + n] = sv;
                tbuf[hrow + n] = tv;
            }
        }
    }
}

// ---------------------------------------------------------------- kernel 2
// Fused attn+epilogue. Block = (b, 32-row i-tile), full j-span, 4 waves.
// Wave w = j-quarter w of each 128-col stage, computing ALL 4 heads
// (adj/msk LDS reads amortized 4x). Staging: global_load_lds width 16,
// double-buffered, XOR-swizzled source (slot ^= row&7 at 16B granularity)
// so ds_read_b128 per-row reads are 2-way (free). Epilogue: cross-wave
// acc/l/A merge in LDS (reuses staging space), /l, bias, BN, ReLU,
// LDS transpose, coalesced out; per-(block,head) eloss partial.
__global__ __launch_bounds__(256, 1) void attn_kernel(
    const float* __restrict__ adj, const float* __restrict__ msk,
    const unsigned short* __restrict__ featsT,
    const float* __restrict__ sbuf, const float* __restrict__ tbuf,
    const float* __restrict__ bias, const float* __restrict__ gamma,
    const float* __restrict__ beta, const float* __restrict__ mmean,
    const float* __restrict__ mvar,
    float* __restrict__ lossbuf, float* __restrict__ out)
{
    // carve one LDS block: adj[2][32][128] | msk[2][32][128] | t[2][4][128] | ldso
    __shared__ __align__(16) float smem[17408 + IT_ * 132];
    float* ladj = smem;            // 8192 floats
    float* lmsk = smem + 8192;     // 8192 floats
    float* lt   = smem + 16384;    // 1024 floats
    float* ldso = smem + 17408;    // 32*132 floats

    const int blk = blockIdx.x;
    const int b = blk >> 6, it = blk & 63;
    const int t = threadIdx.x, w = t >> 6, lane = t & 63;
    const int quad = lane >> 4, r = lane & 15;
    const int i0 = it * IT_;
    const int jt = w * 32 + quad * 8;          // this wave's col window in stage

    float si0[H_], si1[H_];
#pragma unroll
    for (int hh = 0; hh < H_; ++hh) {
        size_t hrow = ((size_t)b * H_ + hh) * N_;
        si0[hh] = sbuf[hrow + i0 + r];
        si1[hh] = sbuf[hrow + i0 + 16 + r];
    }
    // featsT base: hh=0, d=r, col=jt; per-head offset hh*FP_*N_, d+16 -> +16*N_
    const unsigned short* fb =
        featsT + ((size_t)b * H_ * FP_ + r) * N_ + jt;

    // staging sources: instr i=4w+ii covers LDS rows 2i,2i+1; lane: row=+(l>>5),
    // slot s=l&31; content at slot s = global cols ((s ^ (row&7))*4 ..+3)
    const int sl = lane & 31;
    const float* asrc[4];
    const float* msrc[4];
#pragma unroll
    for (int ii = 0; ii < 4; ++ii) {
        int row = 8 * w + 2 * ii + (lane >> 5);
        int cs = (sl ^ (row & 7)) << 2;
        size_t go = ((size_t)b * N_ + i0 + row) * N_ + cs;
        asrc[ii] = adj + go;
        msrc[ii] = msk + go;
    }
    // t staging (waves 2,3): instr covers 2 head-rows of [4][128], linear
    const float* tsrc = tbuf + ((size_t)b * H_ + ((2 * (w & 1)) + (lane >> 5))) * N_ + sl * 4;

    f32x4 acc[H_][4];
#pragma unroll
    for (int hh = 0; hh < H_; ++hh)
#pragma unroll
        for (int k = 0; k < 4; ++k) acc[hh][k] = (f32x4){0.f, 0.f, 0.f, 0.f};
    float l0[H_] = {0.f, 0.f, 0.f, 0.f}, l1[H_] = {0.f, 0.f, 0.f, 0.f};
    float A0[H_] = {0.f, 0.f, 0.f, 0.f}, A1[H_] = {0.f, 0.f, 0.f, 0.f};

    auto STAGE = [&](int buf, int st) {
        const int j0 = st * JST_;
        float* ab = ladj + buf * 4096 + w * 1024;
        float* mb = lmsk + buf * 4096 + w * 1024;
#pragma unroll
        for (int ii = 0; ii < 4; ++ii) {
            gl_lds16(asrc[ii] + j0, ab + ii * 256);
            gl_lds16(msrc[ii] + j0, mb + ii * 256);
        }
        if (w >= 2) gl_lds16(tsrc + j0, lt + buf * 512 + (w - 2) * 256);
    };

    STAGE(0, 0);
    __syncthreads();                     // drain vmcnt + join (buf0 ready)

    for (int st = 0; st < NST_; ++st) {
        const int buf = st & 1;
        if (st + 1 < NST_) STAGE(buf ^ 1, st + 1);   // prefetch next stage
        const int j0 = st * JST_;
        short8v bv[H_][2];
#pragma unroll
        for (int hh = 0; hh < H_; ++hh) {            // L2-resident featsT
            bv[hh][0] = *(const short8v*)(fb + (size_t)hh * FP_ * N_ + j0);
            bv[hh][1] = *(const short8v*)(fb + (size_t)hh * FP_ * N_ + (size_t)16 * N_ + j0);
        }
        const float* ab = ladj + buf * 4096;
        const float* mb = lmsk + buf * 4096;
        const int s0 = ((jt >> 2) ^ (r & 7)) << 2;          // swizzled slots
        const int s1 = (((jt + 4) >> 2) ^ (r & 7)) << 2;    // (r+16 same &7)
        float4 a0l = *(const float4*)(ab + r * 128 + s0);
        float4 a0h = *(const float4*)(ab + r * 128 + s1);
        float4 a1l = *(const float4*)(ab + (r + 16) * 128 + s0);
        float4 a1h = *(const float4*)(ab + (r + 16) * 128 + s1);
        float4 m0l = *(const float4*)(mb + r * 128 + s0);
        float4 m0h = *(const float4*)(mb + r * 128 + s1);
        float4 m1l = *(const float4*)(mb + (r + 16) * 128 + s0);
        float4 m1h = *(const float4*)(mb + (r + 16) * 128 + s1);
        float av0[8] = {a0l.x, a0l.y, a0l.z, a0l.w, a0h.x, a0h.y, a0h.z, a0h.w};
        float av1[8] = {a1l.x, a1l.y, a1l.z, a1l.w, a1h.x, a1h.y, a1h.z, a1h.w};
        float mv0[8] = {m0l.x, m0l.y, m0l.z, m0l.w, m0h.x, m0h.y, m0h.z, m0h.w};
        float mv1[8] = {m1l.x, m1l.y, m1l.z, m1l.w, m1h.x, m1h.y, m1h.z, m1h.w};
#pragma unroll
        for (int hh = 0; hh < H_; ++hh) {            // adj/msk reused 4x here
            float4 t0 = *(const float4*)(lt + buf * 512 + hh * 128 + jt);
            float4 t1 = *(const float4*)(lt + buf * 512 + hh * 128 + jt + 4);
            float tv[8] = {t0.x, t0.y, t0.z, t0.w, t1.x, t1.y, t1.z, t1.w};
            PkU ap0, ap1;
            attn_qstep(si0[hh], av0, mv0, tv, l0[hh], A0[hh], ap0.i);
            attn_qstep(si1[hh], av1, mv1, tv, l1[hh], A1[hh], ap1.i);
            acc[hh][0] = __builtin_amdgcn_mfma_f32_16x16x32_bf16(ap0.s, bv[hh][0], acc[hh][0], 0, 0, 0);
            acc[hh][1] = __builtin_amdgcn_mfma_f32_16x16x32_bf16(ap0.s, bv[hh][1], acc[hh][1], 0, 0, 0);
            acc[hh][2] = __builtin_amdgcn_mfma_f32_16x16x32_bf16(ap1.s, bv[hh][0], acc[hh][2], 0, 0, 0);
            acc[hh][3] = __builtin_amdgcn_mfma_f32_16x16x32_bf16(ap1.s, bv[hh][1], acc[hh][3], 0, 0, 0);
        }
        __syncthreads();               // next buf staged + this buf consumed
    }

    // fold j-subgroup lanes (quads) -> row totals in lanes 0-15, per head
#pragma unroll
    for (int hh = 0; hh < H_; ++hh) {
        l0[hh] += __shfl_down(l0[hh], 32); l0[hh] += __shfl_down(l0[hh], 16);
        l1[hh] += __shfl_down(l1[hh], 32); l1[hh] += __shfl_down(l1[hh], 16);
        A0[hh] += __shfl_down(A0[hh], 32); A0[hh] += __shfl_down(A0[hh], 16);
        A1[hh] += __shfl_down(A1[hh], 32); A1[hh] += __shfl_down(A1[hh], 16);
    }

    // cross-wave merge (reuses staging LDS; safe after loop's final barrier)
    float* mrg = smem;                 // [head][wave][k][256]  (64 KB)
    float* mlA = smem + 16384;         // [head][wave][4][16]   (4 KB, old t)
#pragma unroll
    for (int hh = 0; hh < H_; ++hh)
#pragma unroll
        for (int k = 0; k < 4; ++k)
            *(f32x4*)&mrg[((hh * 4 + w) * 4 + k) * 256 + lane * 4] = acc[hh][k];
    if (lane < 16) {
#pragma unroll
        for (int hh = 0; hh < H_; ++hh) {
            int base = ((hh * 4 + w) * 4) * 16 + lane;
            mlA[base]      = l0[hh];
            mlA[base + 16] = l1[hh];
            mlA[base + 32] = A0[hh];
            mlA[base + 48] = A1[hh];
        }
    }
    __syncthreads();

    // wave w owns head w from here on
    f32x4 C[4];
#pragma unroll
    for (int k = 0; k < 4; ++k) {
        f32x4 c = *(const f32x4*)&mrg[((w * 4 + 0) * 4 + k) * 256 + lane * 4];
#pragma unroll
        for (int w2 = 1; w2 < 4; ++w2)
            c += *(const f32x4*)&mrg[((w * 4 + w2) * 4 + k) * 256 + lane * 4];
        C[k] = c;
    }
    float L0 = 1.f, L1 = 1.f;
    if (lane < 16) {
        float E0 = 0.f, E1 = 0.f;
        L0 = 0.f; L1 = 0.f;
#pragma unroll
        for (int w2 = 0; w2 < 4; ++w2) {
            int base = ((w * 4 + w2) * 4) * 16 + lane;
            L0 += mlA[base];
            L1 += mlA[base + 16];
            E0 += mlA[base + 32];
            E1 += mlA[base + 48];
        }
        float e = E0 / L0 + E1 / L1;   // eloss rows: A/l per row, 2 rowsets
#pragma unroll
        for (int off = 8; off; off >>= 1) e += __shfl_down(e, off);
        if (lane == 0) lossbuf[blk * H_ + w] = e;
    }
    // broadcast per-row l to all lanes (source lanes 0-15 hold valid L0/L1)
    float shL0[4], shL1[4];
#pragma unroll
    for (int rrr = 0; rrr < 4; ++rrr) {
        shL0[rrr] = __shfl(L0, quad * 4 + rrr);
        shL1[rrr] = __shfl(L1, quad * 4 + rrr);
    }
#pragma unroll
    for (int dt = 0; dt < 2; ++dt) {
        int c = w * FP_ + dt * 16 + r;
        float sc = rsqrtf(mvar[c] + 1e-3f) * gamma[c];
        float sh = beta[c] - mmean[c] * sc;
        float bi = bias[c];
#pragma unroll
        for (int rs = 0; rs < 2; ++rs) {
            f32x4 Cv = C[rs * 2 + dt];
#pragma unroll
            for (int rrr = 0; rrr < 4; ++rrr) {
                int row = rs * 16 + quad * 4 + rrr;
                float Lr = rs ? shL1[rrr] : shL0[rrr];
                float node = Cv[rrr] / Lr + bi;
                float o = node * sc + sh;
                ldso[row * 132 + c] = o > 0.f ? o : 0.f;
            }
        }
    }
    __syncthreads();
#pragma unroll
    for (int ps = 0; ps < 4; ++ps) {
        int s = ps * 256 + t;
        int row = s >> 5, c4 = (s & 31) * 4;
        *(float4*)(out + ((size_t)b * N_ + i0 + row) * C_ + c4) =
            *(const float4*)&ldso[row * 132 + c4];
    }
}

// ---------------------------------------------------------------- kernel 3
__global__ __launch_bounds__(256) void loss_kernel(
    const float* __restrict__ lossbuf, float* __restrict__ out)
{
    float e = 0.f;
    for (int idx = threadIdx.x; idx < B_ * ITILES_ * H_; idx += 256)
        e += lossbuf[idx];
    __shared__ float se[256];
    se[threadIdx.x] = e;
    __syncthreads();
    for (int o = 128; o; o >>= 1) {
        if (threadIdx.x < o) se[threadIdx.x] += se[threadIdx.x + o];
        __syncthreads();
    }
    if (threadIdx.x == 0) {
        out[(size_t)B_ * N_ * C_]     = 0.f;                 // uloss == 0 exactly
        out[(size_t)B_ * N_ * C_ + 1] = se[0] * (1.f / N_);  // eloss
    }
}

// ---------------------------------------------------------------- launch
extern "C" void kernel_launch(void* const* d_in, const int* in_sizes, int n_in,
                              void* d_out, int out_size, void* d_ws, size_t ws_size,
                              hipStream_t stream)
{
    const float* x         = (const float*)d_in[0];
    const float* adj       = (const float*)d_in[1];
    const float* attn_mask = (const float*)d_in[2];
    const float* W         = (const float*)d_in[3];
    const float* a_self    = (const float*)d_in[4];
    const float* a_neigh   = (const float*)d_in[5];
    const float* bias      = (const float*)d_in[6];
    const float* gamma     = (const float*)d_in[7];
    const float* beta      = (const float*)d_in[8];
    const float* mmean     = (const float*)d_in[9];
    const float* mvar      = (const float*)d_in[10];
    float* out = (float*)d_out;

    float* ws = (float*)d_ws;
    unsigned short* featsT = (unsigned short*)ws;            // 1,048,576 u16
    float* sbuf  = ws + 524288;                              //    32,768 f
    float* tbuf  = sbuf + (size_t)B_ * H_ * N_;              //    32,768 f
    float* lossb = tbuf + (size_t)B_ * H_ * N_;              //     1,024 f

    hipLaunchKernelGGL(prep_kernel, dim3(B_ * 32), dim3(256), 0, stream,
                       x, W, a_self, a_neigh, featsT, sbuf, tbuf);
    hipLaunchKernelGGL(attn_kernel, dim3(B_ * ITILES_), dim3(256), 0, stream,
                       adj, attn_mask, featsT, sbuf, tbuf, bias, gamma, beta,
                       mmean, mvar, lossb, out);
    hipLaunchKernelGGL(loss_kernel, dim3(1), dim3(256), 0, stream,
                       lossb, out);
}